// Round 10
// baseline (176.717 us; speedup 1.0000x reference)
//
#include <hip/hip_runtime.h>
#include <hip/hip_bf16.h>

#define DEV __device__ __forceinline__

typedef unsigned short u16;
typedef unsigned int   u32;
typedef __attribute__((ext_vector_type(8))) short bf16x8;
typedef __attribute__((ext_vector_type(4))) float f32x4;

DEV float bf2f(u32 v){ return __uint_as_float(v << 16); }
DEV short bfbits(float f){
  __hip_bfloat16 h = __float2bfloat16(f);   // RNE
  return __builtin_bit_cast(short, h);
}
DEV u16 f2bf(float f){ return (u16)bfbits(f); }
DEV u32 pk2(float lo, float hi){
  return (u32)f2bf(lo) | ((u32)f2bf(hi) << 16);
}
DEV float comp(float4 v, int i){ return i==0 ? v.x : (i==1 ? v.y : (i==2 ? v.z : v.w)); }

// all-thread block reduction (256 threads)
DEV void blockReduce2(float& s, float& s2, float* ps, float* ps2, int tid){
  #pragma unroll
  for (int o = 32; o > 0; o >>= 1){ s += __shfl_xor(s, o); s2 += __shfl_xor(s2, o); }
  int w = tid >> 6;
  if ((tid & 63) == 0){ ps[w] = s; ps2[w] = s2; }
  __syncthreads();
  s  = ps[0] + ps[1] + ps[2] + ps[3];
  s2 = ps2[0] + ps2[1] + ps2[2] + ps2[3];
}

// K0: LN1 over C=256 per (b,n) row. grid=6272, block=256. out: bf16
__global__ __launch_bounds__(256) void kLN1(const float* __restrict__ x, const float* __restrict__ g,
                                            const float* __restrict__ be, u16* __restrict__ xn){
  __shared__ float ps[4], ps2[4];
  int bn = blockIdx.x, t = threadIdx.x;
  float v = x[(size_t)bn*256 + t];
  float s = v, s2 = v*v;
  blockReduce2(s, s2, ps, ps2, t);
  float m  = s * (1.f/256.f);
  float var = s2 * (1.f/256.f) - m*m;
  float rs = rsqrtf(var + 1e-3f);
  xn[(size_t)bn*256 + t] = f2bf((v - m)*rs*g[t] + be[t]);
}

// K1 (MFMA, fused LN2-stats): per-n GEMM [32x256]@[256x1536] + b1 + exact gelu -> y bf16.
// Column remap: tile nt, frag-col c -> e = e0 + w*64 + c*4 + nt.
// Blocks with et<3 (u half) accumulate per-row (s, s2) into statsAcc via atomics.
__global__ __launch_bounds__(256) void kExpand(const u16* __restrict__ xn, const float* __restrict__ W1,
                                               const float* __restrict__ b1, u16* __restrict__ y,
                                               float2* __restrict__ statsAcc){
  __shared__ unsigned char smA[16384];     // [32 b][256 k] bf16, 512 B pitch, XOR-swizzled
  int bid = blockIdx.x;
  int n = bid / 6, et = bid % 6;
  int tid = threadIdx.x;
  int e0 = et*256;

  // ---- stage A: xn[b][n][0..255] bf16 -> LDS, swizzled (copy only) ----
  {
    int r = tid >> 3;
    const unsigned char* src = (const unsigned char*)(xn + ((size_t)(r*196 + n))*256);
    #pragma unroll
    for (int i = 0; i < 4; ++i){
      int g = (tid & 7) + 8*i;
      uint4 wv = *(const uint4*)(src + g*16);
      int byte = r*512 + ((g*16) ^ ((r & 7) << 4));
      *(uint4*)(smA + byte) = wv;
    }
  }

  int w = tid >> 6, l = tid & 63;
  int c4 = (l & 15) * 4;
  int ebase = e0 + w*64 + c4;                          // lane's 4 consecutive e-columns
  int kb  = (l >> 4) * 8;
  const float* wb = W1 + (size_t)n*393216 + (size_t)kb*1536 + ebase;

  f32x4 acc[2][4];
  #pragma unroll
  for (int mt = 0; mt < 2; ++mt)
    #pragma unroll
    for (int nt = 0; nt < 4; ++nt)
      acc[mt][nt] = (f32x4){0.f, 0.f, 0.f, 0.f};

  float4 cur[8], nxt[8];
  #pragma unroll
  for (int j = 0; j < 8; ++j)
    cur[j] = *(const float4*)(wb + (size_t)j*1536);

  __syncthreads();                                     // A visible (only barrier)

  #pragma unroll
  for (int ks = 0; ks < 8; ++ks){
    if (ks < 7){
      const float* wn = wb + (size_t)(ks+1)*32*1536;
      #pragma unroll
      for (int j = 0; j < 8; ++j)
        nxt[j] = *(const float4*)(wn + (size_t)j*1536);
    }
    bf16x8 bfr[4];
    #pragma unroll
    for (int nt = 0; nt < 4; ++nt)
      #pragma unroll
      for (int j = 0; j < 8; ++j)
        bfr[nt][j] = bfbits(comp(cur[j], nt));
    bf16x8 afr[2];
    #pragma unroll
    for (int mt = 0; mt < 2; ++mt){
      int row = mt*16 + (l & 15);
      int kbyte = ks*64 + ((l >> 4) << 4);
      afr[mt] = *(const bf16x8*)(smA + row*512 + (kbyte ^ ((row & 7) << 4)));
    }
    #pragma unroll
    for (int mt = 0; mt < 2; ++mt)
      #pragma unroll
      for (int nt = 0; nt < 4; ++nt)
        acc[mt][nt] = __builtin_amdgcn_mfma_f32_16x16x32_bf16(afr[mt], bfr[nt], acc[mt][nt], 0, 0, 0);
    if (ks < 7){
      #pragma unroll
      for (int j = 0; j < 8; ++j)
        cur[j] = nxt[j];
    }
  }

  // ---- epilogue: bias + exact gelu + packed uint2 stores; (et<3) LN2 stats ----
  bool doStats = (et < 3);
  float4 bb = *(const float4*)(b1 + (size_t)n*1536 + ebase);
  float ss[2][4], ss2[2][4];
  #pragma unroll
  for (int mt = 0; mt < 2; ++mt){
    #pragma unroll
    for (int r = 0; r < 4; ++r){
      int b = mt*16 + ((l >> 4) << 2) + r;             // C/D: row=(lane>>4)*4+reg
      float v0 = acc[mt][0][r] + bb.x;
      float v1 = acc[mt][1][r] + bb.y;
      float v2 = acc[mt][2][r] + bb.z;
      float v3 = acc[mt][3][r] + bb.w;
      v0 = 0.5f*v0*(1.f + erff(v0*0.70710678118654752f));
      v1 = 0.5f*v1*(1.f + erff(v1*0.70710678118654752f));
      v2 = 0.5f*v2*(1.f + erff(v2*0.70710678118654752f));
      v3 = 0.5f*v3*(1.f + erff(v3*0.70710678118654752f));
      *(uint2*)(y + ((size_t)(b*196 + n))*1536 + ebase) = make_uint2(pk2(v0,v1), pk2(v2,v3));
      ss[mt][r]  = v0 + v1 + v2 + v3;
      ss2[mt][r] = v0*v0 + v1*v1 + v2*v2 + v3*v3;
    }
  }
  if (doStats){
    #pragma unroll
    for (int mt = 0; mt < 2; ++mt){
      #pragma unroll
      for (int r = 0; r < 4; ++r){
        float a = ss[mt][r], b = ss2[mt][r];
        #pragma unroll
        for (int o = 1; o < 16; o <<= 1){ a += __shfl_xor(a, o); b += __shfl_xor(b, o); }
        if ((l & 15) == 0){
          int brow = mt*16 + ((l >> 4) << 2) + r;
          float2* sp = &statsAcc[brow*196 + n];
          atomicAdd(&sp->x, a);
          atomicAdd(&sp->y, b);
        }
      }
    }
  }
}

// K3/K5: 64x64 tiled bf16 transpose [R rows x Cc cols] -> [Cc x R].
// If statsAcc!=null, finalizes LN2 (m,rstd from raw (s,s2)) and applies affine to c<768.
__global__ __launch_bounds__(256) void kTrans(const u16* __restrict__ in, u16* __restrict__ out,
                                              int R, int Cc, const float2* __restrict__ statsAcc,
                                              const float* __restrict__ g2, const float* __restrict__ be2){
  __shared__ float T[64][65];
  int ntc = Cc >> 6;
  int rt = blockIdx.x / ntc, ct = blockIdx.x % ntc;
  int r0 = rt << 6, c0 = ct << 6;
  int l = threadIdx.x & 63, q = threadIdx.x >> 6;
  bool doLN = (statsAcc != nullptr) && (c0 < 768);
  float gv = 1.f, bv = 0.f;
  if (doLN){ gv = g2[c0 + l]; bv = be2[c0 + l]; }
  #pragma unroll
  for (int i = 0; i < 16; ++i){
    int r = (i << 2) + q;
    float val = bf2f(in[(size_t)(r0 + r)*Cc + c0 + l]);
    if (doLN){
      float2 st = statsAcc[r0 + r];
      float m = st.x * (1.f/768.f);
      float var = st.y * (1.f/768.f) - m*m;
      float rs = rsqrtf(var + 1e-3f);
      val = (val - m)*rs*gv + bv;
    }
    T[l][r] = val;
  }
  __syncthreads();
  #pragma unroll
  for (int i = 0; i < 16; ++i){
    int c = (i << 2) + q;
    out[(size_t)(c0 + c)*R + r0 + l] = f2bf(T[c][l]);
  }
}

// K4 (MFMA): per-d GEMM [32(b) x 196] @ W2[d][196 x 196] + b2^T, times v -> zT bf16.
__global__ __launch_bounds__(256) void kSGU(const u16* __restrict__ yT, const float* __restrict__ W2,
                                            const float* __restrict__ b2, u16* __restrict__ zT){
  __shared__ unsigned char smA[16384];     // [32 b][256 m] bf16, 512 B pitch, swizzled
  int d = blockIdx.x, tid = threadIdx.x;
  const u16* up = yT + (size_t)d*6272;     // u^T[d]: [32 b][196 m] bf16

  // ---- stage A (predicated m<196, zero-padded to 256) ----
  {
    int r = tid >> 3;
    const unsigned char* srcb = (const unsigned char*)(up + r*196);
    #pragma unroll
    for (int i = 0; i < 4; ++i){
      int g = (tid & 7) + 8*i;
      int k0 = g*8;
      uint4 wv;
      if (k0 + 8 <= 196){
        uint2 lo = *(const uint2*)(srcb + k0*2);
        uint2 hi = *(const uint2*)(srcb + k0*2 + 8);
        wv = make_uint4(lo.x, lo.y, hi.x, hi.y);
      } else {
        const u16* s16 = (const u16*)srcb;
        u16 tmp[8];
        #pragma unroll
        for (int j = 0; j < 8; ++j){
          int k = k0 + j;
          tmp[j] = (k < 196) ? s16[k] : (u16)0;
        }
        wv.x = (u32)tmp[0] | ((u32)tmp[1] << 16);
        wv.y = (u32)tmp[2] | ((u32)tmp[3] << 16);
        wv.z = (u32)tmp[4] | ((u32)tmp[5] << 16);
        wv.w = (u32)tmp[6] | ((u32)tmp[7] << 16);
      }
      int byte = r*512 + ((g*16) ^ ((r & 7) << 4));
      *(uint4*)(smA + byte) = wv;
    }
  }

  int w = tid >> 6, l = tid & 63;
  int kb = (l >> 4) * 8;
  int nb = w*64 + (l & 15)*4;                          // lane's 4 consecutive n-columns
  int nload = nb > 192 ? 192 : nb;                     // clamp float4 in-bounds
  const float* w2d = W2 + (size_t)d*38416;

  f32x4 acc[2][4];
  #pragma unroll
  for (int mt = 0; mt < 2; ++mt)
    #pragma unroll
    for (int nt = 0; nt < 4; ++nt)
      acc[mt][nt] = (f32x4){0.f, 0.f, 0.f, 0.f};

  float4 cur[8], nxt[8];
  #pragma unroll
  for (int j = 0; j < 8; ++j)
    cur[j] = *(const float4*)(w2d + (size_t)(kb + j)*196 + nload);

  __syncthreads();

  for (int ks = 0; ks < 7; ++ks){
    if (ks < 6){
      #pragma unroll
      for (int j = 0; j < 8; ++j){
        int k = (ks+1)*32 + kb + j;
        int kcl = k < 196 ? k : 195;
        nxt[j] = *(const float4*)(w2d + (size_t)kcl*196 + nload);
      }
    }
    bf16x8 afr[2];
    #pragma unroll
    for (int mt = 0; mt < 2; ++mt){
      int row = mt*16 + (l & 15);
      int kbyte = ks*64 + ((l >> 4) << 4);
      afr[mt] = *(const bf16x8*)(smA + row*512 + (kbyte ^ ((row & 7) << 4)));
    }
    #pragma unroll
    for (int nt = 0; nt < 4; ++nt){
      bf16x8 bfr;
      #pragma unroll
      for (int j = 0; j < 8; ++j)
        bfr[j] = bfbits(comp(cur[j], nt));
      acc[0][nt] = __builtin_amdgcn_mfma_f32_16x16x32_bf16(afr[0], bfr, acc[0][nt], 0, 0, 0);
      acc[1][nt] = __builtin_amdgcn_mfma_f32_16x16x32_bf16(afr[1], bfr, acc[1][nt], 0, 0, 0);
    }
    if (ks < 6){
      #pragma unroll
      for (int j = 0; j < 8; ++j)
        cur[j] = nxt[j];
    }
  }

  // ---- epilogue: +b2^T, *v, packed uint2 store (valid iff nb <= 192) ----
  if (nb <= 192){
    float4 b2v = *(const float4*)(b2 + (size_t)d*196 + nb);
    const u16* vrow = yT + (size_t)4816896 + (size_t)d*6272;
    u16* zrow = zT + (size_t)d*6272;
    #pragma unroll
    for (int mt = 0; mt < 2; ++mt){
      #pragma unroll
      for (int r = 0; r < 4; ++r){
        int b = mt*16 + ((l >> 4) << 2) + r;
        uint2 vv = *(const uint2*)(vrow + (size_t)b*196 + nb);
        float z0 = (acc[mt][0][r] + b2v.x) * bf2f(vv.x & 0xFFFF);
        float z1 = (acc[mt][1][r] + b2v.y) * bf2f(vv.x >> 16);
        float z2 = (acc[mt][2][r] + b2v.z) * bf2f(vv.y & 0xFFFF);
        float z3 = (acc[mt][3][r] + b2v.w) * bf2f(vv.y >> 16);
        *(uint2*)(zrow + (size_t)b*196 + nb) = make_uint2(pk2(z0,z1), pk2(z2,z3));
      }
    }
  }
}

// K6 (MFMA, fused epilogue): per-n GEMM [32x768]@[768x256] + b3 + x -> out fp32.
// grid=196, block=512 (8 waves). Wave w: c-quadrant q=w&3, K-half kh=w>>2 (384 each).
__global__ __launch_bounds__(512) void kOutF(const u16* __restrict__ z, const float* __restrict__ W3,
                                             const float* __restrict__ b3, const float* __restrict__ x,
                                             float* __restrict__ out){
  __shared__ unsigned char smA[49152];     // [32 b][768 d] bf16, 1536 B pitch, swizzled
  int n = blockIdx.x;
  int tid = threadIdx.x;

  // ---- stage A: z[b][n*768 .. +768] bf16 -> LDS (512 thr, 6 x uint4 each) ----
  {
    int r = tid >> 4;                                  // b row 0..31
    const unsigned char* src = (const unsigned char*)(z + ((size_t)(r*196 + n))*768);
    #pragma unroll
    for (int i = 0; i < 6; ++i){
      int g = (tid & 15) + 16*i;                       // 16B-group 0..95
      uint4 wv = *(const uint4*)(src + g*16);
      int byte = r*1536 + ((g*16) ^ ((r & 7) << 4));
      *(uint4*)(smA + byte) = wv;
    }
  }

  int w = tid >> 6, l = tid & 63;
  int q = w & 3, kh = w >> 2;
  int cbase = q*64 + (l & 15)*4;                       // lane's 4 consecutive c-columns
  int kb  = (l >> 4) * 8;
  const float* wb = W3 + (size_t)n*196608 + (size_t)(kh*384 + kb)*256 + cbase;

  f32x4 acc[2][4];
  #pragma unroll
  for (int mt = 0; mt < 2; ++mt)
    #pragma unroll
    for (int nt = 0; nt < 4; ++nt)
      acc[mt][nt] = (f32x4){0.f, 0.f, 0.f, 0.f};

  float4 cur[8], nxt[8];
  #pragma unroll
  for (int j = 0; j < 8; ++j)
    cur[j] = *(const float4*)(wb + (size_t)j*256);

  __syncthreads();

  for (int ks = 0; ks < 12; ++ks){
    if (ks < 11){
      const float* wn = wb + (size_t)(ks+1)*32*256;
      #pragma unroll
      for (int j = 0; j < 8; ++j)
        nxt[j] = *(const float4*)(wn + (size_t)j*256);
    }
    bf16x8 bfr[4];
    #pragma unroll
    for (int nt = 0; nt < 4; ++nt)
      #pragma unroll
      for (int j = 0; j < 8; ++j)
        bfr[nt][j] = bfbits(comp(cur[j], nt));
    bf16x8 afr[2];
    #pragma unroll
    for (int mt = 0; mt < 2; ++mt){
      int row = mt*16 + (l & 15);
      int kbyte = kh*768 + ks*64 + ((l >> 4) << 4);
      afr[mt] = *(const bf16x8*)(smA + row*1536 + (kbyte ^ ((row & 7) << 4)));
    }
    #pragma unroll
    for (int mt = 0; mt < 2; ++mt)
      #pragma unroll
      for (int nt = 0; nt < 4; ++nt)
        acc[mt][nt] = __builtin_amdgcn_mfma_f32_16x16x32_bf16(afr[mt], bfr[nt], acc[mt][nt], 0, 0, 0);
    if (ks < 11){
      #pragma unroll
      for (int j = 0; j < 8; ++j)
        cur[j] = nxt[j];
    }
  }

  // ---- cross-wave K reduction: waves 4-7 dump to LDS, waves 0-3 add ----
  __syncthreads();                                     // all A-frag reads done
  float* red = (float*)smA;                            // [256][33] fp32, conflict-free
  if (kh == 1){
    int t4 = tid - 256;
    #pragma unroll
    for (int mt = 0; mt < 2; ++mt)
      #pragma unroll
      for (int nt = 0; nt < 4; ++nt)
        #pragma unroll
        for (int r = 0; r < 4; ++r)
          red[t4*33 + mt*16 + nt*4 + r] = acc[mt][nt][r];
  }
  __syncthreads();
  if (kh == 0){
    #pragma unroll
    for (int mt = 0; mt < 2; ++mt)
      #pragma unroll
      for (int nt = 0; nt < 4; ++nt)
        #pragma unroll
        for (int r = 0; r < 4; ++r)
          acc[mt][nt][r] += red[tid*33 + mt*16 + nt*4 + r];

    // ---- epilogue: + b3 + x residual -> out fp32 (float4 stores) ----
    float4 bb = *(const float4*)(b3 + (size_t)n*256 + cbase);
    #pragma unroll
    for (int mt = 0; mt < 2; ++mt){
      #pragma unroll
      for (int r = 0; r < 4; ++r){
        int b = mt*16 + ((l >> 4) << 2) + r;
        size_t o = ((size_t)(b*196 + n))*256 + cbase;
        float4 xv = *(const float4*)(x + o);
        float4 ov;
        ov.x = acc[mt][0][r] + bb.x + xv.x;
        ov.y = acc[mt][1][r] + bb.y + xv.y;
        ov.z = acc[mt][2][r] + bb.z + xv.z;
        ov.w = acc[mt][3][r] + bb.w + xv.w;
        *(float4*)(out + o) = ov;
      }
    }
  }
}

extern "C" void kernel_launch(void* const* d_in, const int* in_sizes, int n_in,
                              void* d_out, int out_size, void* d_ws, size_t ws_size,
                              hipStream_t stream){
  const float* x   = (const float*)d_in[0];
  const float* g1  = (const float*)d_in[1];
  const float* be1 = (const float*)d_in[2];
  const float* W1  = (const float*)d_in[3];
  const float* b1  = (const float*)d_in[4];
  const float* g2  = (const float*)d_in[5];
  const float* be2 = (const float*)d_in[6];
  const float* W2  = (const float*)d_in[7];
  const float* b2  = (const float*)d_in[8];
  const float* W3  = (const float*)d_in[9];
  const float* b3  = (const float*)d_in[10];
  float* out = (float*)d_out;

  char* ws = (char*)d_ws;
  size_t off = 0;
  auto alloc = [&](size_t bytes) -> void* {
    void* p = ws + off;
    off += (bytes + 255) & ~(size_t)255;
    return p;
  };
  u16*    xn    = (u16*)   alloc((size_t)1605632*2);   // LN1 out, bf16
  u16*    y     = (u16*)   alloc((size_t)9633792*2);   // [6272][1536] bf16; reused for zT+z
  float2* stats = (float2*)alloc((size_t)6272*8);      // LN2 raw (s, s2) accumulators
  u16*    yT    = (u16*)   alloc((size_t)9633792*2);   // [1536][6272] bf16
  if (off > ws_size) return;

  u16* zT = y;                 // [768][6272] bf16 (y dead by kSGU)
  u16* z  = y + 4816896;       // [6272][768] bf16

  hipMemsetAsync(stats, 0, (size_t)6272*8, stream);
  kLN1   <<<6272, 256, 0, stream>>>(x, g1, be1, xn);
  kExpand<<<1176, 256, 0, stream>>>(xn, W1, b1, y, stats);
  kTrans <<<2352, 256, 0, stream>>>(y, yT, 6272, 1536, stats, g2, be2);
  kSGU   <<<768,  256, 0, stream>>>(yT, W2, b2, zT);
  kTrans <<<1176, 256, 0, stream>>>(zT, z, 768, 6272, nullptr, nullptr, nullptr);
  kOutF  <<<196,  512, 0, stream>>>(z, W3, b3, x, out);
}

// Round 12
// 160.076 us; speedup vs baseline: 1.1040x; 1.1040x over previous
//
#include <hip/hip_runtime.h>
#include <hip/hip_bf16.h>

#define DEV __device__ __forceinline__

typedef unsigned short u16;
typedef unsigned int   u32;
typedef __attribute__((ext_vector_type(8))) short bf16x8;
typedef __attribute__((ext_vector_type(4))) float f32x4;

DEV float bf2f(u32 v){ return __uint_as_float(v << 16); }
DEV short bfbits(float f){
  __hip_bfloat16 h = __float2bfloat16(f);   // RNE
  return __builtin_bit_cast(short, h);
}
DEV u16 f2bf(float f){ return (u16)bfbits(f); }
DEV u32 pk2(float lo, float hi){
  return (u32)f2bf(lo) | ((u32)f2bf(hi) << 16);
}
// non-temporal float4 load (native vector type — HIP_vector_type is rejected by the builtin):
// stream-once weights must not evict L2/L3-resident activations
DEV f32x4 ldnt4(const float* p){ return __builtin_nontemporal_load((const f32x4*)p); }

// all-thread block reduction (256 threads)
DEV void blockReduce2(float& s, float& s2, float* ps, float* ps2, int tid){
  #pragma unroll
  for (int o = 32; o > 0; o >>= 1){ s += __shfl_xor(s, o); s2 += __shfl_xor(s2, o); }
  int w = tid >> 6;
  if ((tid & 63) == 0){ ps[w] = s; ps2[w] = s2; }
  __syncthreads();
  s  = ps[0] + ps[1] + ps[2] + ps[3];
  s2 = ps2[0] + ps2[1] + ps2[2] + ps2[3];
}

// K0: LN1 over C=256 per (b,n) row. grid=6272, block=256. out: bf16
__global__ __launch_bounds__(256) void kLN1(const float* __restrict__ x, const float* __restrict__ g,
                                            const float* __restrict__ be, u16* __restrict__ xn){
  __shared__ float ps[4], ps2[4];
  int bn = blockIdx.x, t = threadIdx.x;
  float v = x[(size_t)bn*256 + t];
  float s = v, s2 = v*v;
  blockReduce2(s, s2, ps, ps2, t);
  float m  = s * (1.f/256.f);
  float var = s2 * (1.f/256.f) - m*m;
  float rs = rsqrtf(var + 1e-3f);
  xn[(size_t)bn*256 + t] = f2bf((v - m)*rs*g[t] + be[t]);
}

// K1 (MFMA): per-n GEMM [32x256]@[256x1536] + b1 + exact gelu -> y bf16.
// Column remap: tile nt, frag-col c -> e = e0 + w*64 + c*4 + nt  (dwordx4 B loads, uint2 stores)
__global__ __launch_bounds__(256) void kExpand(const u16* __restrict__ xn, const float* __restrict__ W1,
                                               const float* __restrict__ b1, u16* __restrict__ y){
  __shared__ unsigned char smA[16384];     // [32 b][256 k] bf16, 512 B pitch, XOR-swizzled
  int bid = blockIdx.x;
  int n = bid / 6, et = bid % 6;
  int tid = threadIdx.x;
  int e0 = et*256;

  // ---- stage A: xn[b][n][0..255] bf16 -> LDS, swizzled (copy only) ----
  {
    int r = tid >> 3;
    const unsigned char* src = (const unsigned char*)(xn + ((size_t)(r*196 + n))*256);
    #pragma unroll
    for (int i = 0; i < 4; ++i){
      int g = (tid & 7) + 8*i;
      uint4 wv = *(const uint4*)(src + g*16);
      int byte = r*512 + ((g*16) ^ ((r & 7) << 4));
      *(uint4*)(smA + byte) = wv;
    }
  }

  int w = tid >> 6, l = tid & 63;
  int c4 = (l & 15) * 4;
  int ebase = e0 + w*64 + c4;                          // lane's 4 consecutive e-columns
  int kb  = (l >> 4) * 8;
  const float* wb = W1 + (size_t)n*393216 + (size_t)kb*1536 + ebase;

  f32x4 acc[2][4];
  #pragma unroll
  for (int mt = 0; mt < 2; ++mt)
    #pragma unroll
    for (int nt = 0; nt < 4; ++nt)
      acc[mt][nt] = (f32x4){0.f, 0.f, 0.f, 0.f};

  f32x4 cur[8], nxt[8];
  #pragma unroll
  for (int j = 0; j < 8; ++j)
    cur[j] = ldnt4(wb + (size_t)j*1536);

  __syncthreads();                                     // A visible (only barrier)

  #pragma unroll
  for (int ks = 0; ks < 8; ++ks){
    if (ks < 7){
      const float* wn = wb + (size_t)(ks+1)*32*1536;
      #pragma unroll
      for (int j = 0; j < 8; ++j)
        nxt[j] = ldnt4(wn + (size_t)j*1536);
    }
    bf16x8 bfr[4];
    #pragma unroll
    for (int nt = 0; nt < 4; ++nt)
      #pragma unroll
      for (int j = 0; j < 8; ++j)
        bfr[nt][j] = bfbits(cur[j][nt]);
    bf16x8 afr[2];
    #pragma unroll
    for (int mt = 0; mt < 2; ++mt){
      int row = mt*16 + (l & 15);
      int kbyte = ks*64 + ((l >> 4) << 4);
      afr[mt] = *(const bf16x8*)(smA + row*512 + (kbyte ^ ((row & 7) << 4)));
    }
    #pragma unroll
    for (int mt = 0; mt < 2; ++mt)
      #pragma unroll
      for (int nt = 0; nt < 4; ++nt)
        acc[mt][nt] = __builtin_amdgcn_mfma_f32_16x16x32_bf16(afr[mt], bfr[nt], acc[mt][nt], 0, 0, 0);
    if (ks < 7){
      #pragma unroll
      for (int j = 0; j < 8; ++j)
        cur[j] = nxt[j];
    }
  }

  // ---- epilogue: bias + exact gelu + packed uint2 bf16 stores ----
  float4 bb = *(const float4*)(b1 + (size_t)n*1536 + ebase);
  #pragma unroll
  for (int mt = 0; mt < 2; ++mt){
    #pragma unroll
    for (int r = 0; r < 4; ++r){
      int b = mt*16 + ((l >> 4) << 2) + r;             // C/D: row=(lane>>4)*4+reg
      float v0 = acc[mt][0][r] + bb.x;
      float v1 = acc[mt][1][r] + bb.y;
      float v2 = acc[mt][2][r] + bb.z;
      float v3 = acc[mt][3][r] + bb.w;
      v0 = 0.5f*v0*(1.f + erff(v0*0.70710678118654752f));
      v1 = 0.5f*v1*(1.f + erff(v1*0.70710678118654752f));
      v2 = 0.5f*v2*(1.f + erff(v2*0.70710678118654752f));
      v3 = 0.5f*v3*(1.f + erff(v3*0.70710678118654752f));
      *(uint2*)(y + ((size_t)(b*196 + n))*1536 + ebase) = make_uint2(pk2(v0,v1), pk2(v2,v3));
    }
  }
}

// K2: LN2 stats over H=768 (u half of y bf16) per (b,n). grid=6272, block=256
__global__ __launch_bounds__(256) void kStats2(const u16* __restrict__ y, float2* __restrict__ stats){
  __shared__ float ps[4], ps2[4];
  int bn = blockIdx.x, t = threadIdx.x;
  const u16* r = y + (size_t)bn*1536;
  float a0 = bf2f(r[t]), a1 = bf2f(r[t+256]), a2 = bf2f(r[t+512]);
  float s = a0+a1+a2, s2 = a0*a0 + a1*a1 + a2*a2;
  blockReduce2(s, s2, ps, ps2, t);
  float m   = s * (1.f/768.f);
  float var = s2 * (1.f/768.f) - m*m;
  if (t == 0) stats[bn] = make_float2(m, rsqrtf(var + 1e-3f));
}

// K3/K5: 64x64 tiled bf16 transpose [R rows x Cc cols] -> [Cc x R].
// If stats!=null, applies LN2 affine (fp32 math) to columns c<768 (u half).
__global__ __launch_bounds__(256) void kTrans(const u16* __restrict__ in, u16* __restrict__ out,
                                              int R, int Cc, const float2* __restrict__ stats,
                                              const float* __restrict__ g2, const float* __restrict__ be2){
  __shared__ float T[64][65];
  int ntc = Cc >> 6;
  int rt = blockIdx.x / ntc, ct = blockIdx.x % ntc;
  int r0 = rt << 6, c0 = ct << 6;
  int l = threadIdx.x & 63, q = threadIdx.x >> 6;
  bool doLN = (stats != nullptr) && (c0 < 768);
  float gv = 1.f, bv = 0.f;
  if (doLN){ gv = g2[c0 + l]; bv = be2[c0 + l]; }
  #pragma unroll
  for (int i = 0; i < 16; ++i){
    int r = (i << 2) + q;
    float val = bf2f(in[(size_t)(r0 + r)*Cc + c0 + l]);
    if (doLN){ float2 st = stats[r0 + r]; val = (val - st.x)*st.y*gv + bv; }
    T[l][r] = val;
  }
  __syncthreads();
  #pragma unroll
  for (int i = 0; i < 16; ++i){
    int c = (i << 2) + q;
    out[(size_t)(c0 + c)*R + r0 + l] = f2bf(T[c][l]);
  }
}

// K4 (MFMA): per-d GEMM [32(b) x 196] @ W2[d][196 x 196] + b2^T, times v -> zT bf16.
__global__ __launch_bounds__(256) void kSGU(const u16* __restrict__ yT, const float* __restrict__ W2,
                                            const float* __restrict__ b2, u16* __restrict__ zT){
  __shared__ unsigned char smA[16384];     // [32 b][256 m] bf16, 512 B pitch, swizzled
  int d = blockIdx.x, tid = threadIdx.x;
  const u16* up = yT + (size_t)d*6272;     // u^T[d]: [32 b][196 m] bf16

  // ---- stage A (predicated m<196, zero-padded to 256) ----
  {
    int r = tid >> 3;
    const unsigned char* srcb = (const unsigned char*)(up + r*196);
    #pragma unroll
    for (int i = 0; i < 4; ++i){
      int g = (tid & 7) + 8*i;
      int k0 = g*8;
      uint4 wv;
      if (k0 + 8 <= 196){
        uint2 lo = *(const uint2*)(srcb + k0*2);
        uint2 hi = *(const uint2*)(srcb + k0*2 + 8);
        wv = make_uint4(lo.x, lo.y, hi.x, hi.y);
      } else {
        const u16* s16 = (const u16*)srcb;
        u16 tmp[8];
        #pragma unroll
        for (int j = 0; j < 8; ++j){
          int k = k0 + j;
          tmp[j] = (k < 196) ? s16[k] : (u16)0;
        }
        wv.x = (u32)tmp[0] | ((u32)tmp[1] << 16);
        wv.y = (u32)tmp[2] | ((u32)tmp[3] << 16);
        wv.z = (u32)tmp[4] | ((u32)tmp[5] << 16);
        wv.w = (u32)tmp[6] | ((u32)tmp[7] << 16);
      }
      int byte = r*512 + ((g*16) ^ ((r & 7) << 4));
      *(uint4*)(smA + byte) = wv;
    }
  }

  int w = tid >> 6, l = tid & 63;
  int kb = (l >> 4) * 8;
  int nb = w*64 + (l & 15)*4;                          // lane's 4 consecutive n-columns
  int nload = nb > 192 ? 192 : nb;                     // clamp float4 in-bounds
  const float* w2d = W2 + (size_t)d*38416;

  f32x4 acc[2][4];
  #pragma unroll
  for (int mt = 0; mt < 2; ++mt)
    #pragma unroll
    for (int nt = 0; nt < 4; ++nt)
      acc[mt][nt] = (f32x4){0.f, 0.f, 0.f, 0.f};

  f32x4 cur[8], nxt[8];
  #pragma unroll
  for (int j = 0; j < 8; ++j)
    cur[j] = ldnt4(w2d + (size_t)(kb + j)*196 + nload);

  __syncthreads();

  for (int ks = 0; ks < 7; ++ks){
    if (ks < 6){
      #pragma unroll
      for (int j = 0; j < 8; ++j){
        int k = (ks+1)*32 + kb + j;
        int kcl = k < 196 ? k : 195;
        nxt[j] = ldnt4(w2d + (size_t)kcl*196 + nload);
      }
    }
    bf16x8 afr[2];
    #pragma unroll
    for (int mt = 0; mt < 2; ++mt){
      int row = mt*16 + (l & 15);
      int kbyte = ks*64 + ((l >> 4) << 4);
      afr[mt] = *(const bf16x8*)(smA + row*512 + (kbyte ^ ((row & 7) << 4)));
    }
    #pragma unroll
    for (int nt = 0; nt < 4; ++nt){
      bf16x8 bfr;
      #pragma unroll
      for (int j = 0; j < 8; ++j)
        bfr[j] = bfbits(cur[j][nt]);
      acc[0][nt] = __builtin_amdgcn_mfma_f32_16x16x32_bf16(afr[0], bfr, acc[0][nt], 0, 0, 0);
      acc[1][nt] = __builtin_amdgcn_mfma_f32_16x16x32_bf16(afr[1], bfr, acc[1][nt], 0, 0, 0);
    }
    if (ks < 6){
      #pragma unroll
      for (int j = 0; j < 8; ++j)
        cur[j] = nxt[j];
    }
  }

  // ---- epilogue: +b2^T, *v, packed uint2 store (valid iff nb <= 192) ----
  if (nb <= 192){
    float4 b2v = *(const float4*)(b2 + (size_t)d*196 + nb);
    const u16* vrow = yT + (size_t)4816896 + (size_t)d*6272;
    u16* zrow = zT + (size_t)d*6272;
    #pragma unroll
    for (int mt = 0; mt < 2; ++mt){
      #pragma unroll
      for (int r = 0; r < 4; ++r){
        int b = mt*16 + ((l >> 4) << 2) + r;
        uint2 vv = *(const uint2*)(vrow + (size_t)b*196 + nb);
        float z0 = (acc[mt][0][r] + b2v.x) * bf2f(vv.x & 0xFFFF);
        float z1 = (acc[mt][1][r] + b2v.y) * bf2f(vv.x >> 16);
        float z2 = (acc[mt][2][r] + b2v.z) * bf2f(vv.y & 0xFFFF);
        float z3 = (acc[mt][3][r] + b2v.w) * bf2f(vv.y >> 16);
        *(uint2*)(zrow + (size_t)b*196 + nb) = make_uint2(pk2(z0,z1), pk2(z2,z3));
      }
    }
  }
}

// K6 (MFMA, fused epilogue): per-n GEMM [32x768]@[768x256] + b3 + x -> out fp32.
// grid=196, block=512 (8 waves). Wave w: c-quadrant q=w&3, K-half kh=w>>2 (384 each).
__global__ __launch_bounds__(512) void kOutF(const u16* __restrict__ z, const float* __restrict__ W3,
                                             const float* __restrict__ b3, const float* __restrict__ x,
                                             float* __restrict__ out){
  __shared__ unsigned char smA[49152];     // [32 b][768 d] bf16, 1536 B pitch, swizzled
  int n = blockIdx.x;
  int tid = threadIdx.x;

  // ---- stage A: z[b][n*768 .. +768] bf16 -> LDS (512 thr, 6 x uint4 each) ----
  {
    int r = tid >> 4;                                  // b row 0..31
    const unsigned char* src = (const unsigned char*)(z + ((size_t)(r*196 + n))*768);
    #pragma unroll
    for (int i = 0; i < 6; ++i){
      int g = (tid & 15) + 16*i;                       // 16B-group 0..95
      uint4 wv = *(const uint4*)(src + g*16);
      int byte = r*1536 + ((g*16) ^ ((r & 7) << 4));
      *(uint4*)(smA + byte) = wv;
    }
  }

  int w = tid >> 6, l = tid & 63;
  int q = w & 3, kh = w >> 2;
  int cbase = q*64 + (l & 15)*4;                       // lane's 4 consecutive c-columns
  int kb  = (l >> 4) * 8;
  const float* wb = W3 + (size_t)n*196608 + (size_t)(kh*384 + kb)*256 + cbase;

  f32x4 acc[2][4];
  #pragma unroll
  for (int mt = 0; mt < 2; ++mt)
    #pragma unroll
    for (int nt = 0; nt < 4; ++nt)
      acc[mt][nt] = (f32x4){0.f, 0.f, 0.f, 0.f};

  f32x4 cur[8], nxt[8];
  #pragma unroll
  for (int j = 0; j < 8; ++j)
    cur[j] = ldnt4(wb + (size_t)j*256);

  __syncthreads();

  for (int ks = 0; ks < 12; ++ks){
    if (ks < 11){
      const float* wn = wb + (size_t)(ks+1)*32*256;
      #pragma unroll
      for (int j = 0; j < 8; ++j)
        nxt[j] = ldnt4(wn + (size_t)j*256);
    }
    bf16x8 bfr[4];
    #pragma unroll
    for (int nt = 0; nt < 4; ++nt)
      #pragma unroll
      for (int j = 0; j < 8; ++j)
        bfr[nt][j] = bfbits(cur[j][nt]);
    bf16x8 afr[2];
    #pragma unroll
    for (int mt = 0; mt < 2; ++mt){
      int row = mt*16 + (l & 15);
      int kbyte = kh*768 + ks*64 + ((l >> 4) << 4);
      afr[mt] = *(const bf16x8*)(smA + row*1536 + (kbyte ^ ((row & 7) << 4)));
    }
    #pragma unroll
    for (int mt = 0; mt < 2; ++mt)
      #pragma unroll
      for (int nt = 0; nt < 4; ++nt)
        acc[mt][nt] = __builtin_amdgcn_mfma_f32_16x16x32_bf16(afr[mt], bfr[nt], acc[mt][nt], 0, 0, 0);
    if (ks < 11){
      #pragma unroll
      for (int j = 0; j < 8; ++j)
        cur[j] = nxt[j];
    }
  }

  // ---- cross-wave K reduction: waves 4-7 dump to LDS, waves 0-3 add ----
  __syncthreads();                                     // all A-frag reads done
  float* red = (float*)smA;                            // [256][33] fp32, conflict-free
  if (kh == 1){
    int t4 = tid - 256;
    #pragma unroll
    for (int mt = 0; mt < 2; ++mt)
      #pragma unroll
      for (int nt = 0; nt < 4; ++nt)
        #pragma unroll
        for (int r = 0; r < 4; ++r)
          red[t4*33 + mt*16 + nt*4 + r] = acc[mt][nt][r];
  }
  __syncthreads();
  if (kh == 0){
    #pragma unroll
    for (int mt = 0; mt < 2; ++mt)
      #pragma unroll
      for (int nt = 0; nt < 4; ++nt)
        #pragma unroll
        for (int r = 0; r < 4; ++r)
          acc[mt][nt][r] += red[tid*33 + mt*16 + nt*4 + r];

    // ---- epilogue: + b3 + x residual -> out fp32 (float4 stores) ----
    float4 bb = *(const float4*)(b3 + (size_t)n*256 + cbase);
    #pragma unroll
    for (int mt = 0; mt < 2; ++mt){
      #pragma unroll
      for (int r = 0; r < 4; ++r){
        int b = mt*16 + ((l >> 4) << 2) + r;
        size_t o = ((size_t)(b*196 + n))*256 + cbase;
        float4 xv = *(const float4*)(x + o);
        float4 ov;
        ov.x = acc[mt][0][r] + bb.x + xv.x;
        ov.y = acc[mt][1][r] + bb.y + xv.y;
        ov.z = acc[mt][2][r] + bb.z + xv.z;
        ov.w = acc[mt][3][r] + bb.w + xv.w;
        *(float4*)(out + o) = ov;
      }
    }
  }
}

extern "C" void kernel_launch(void* const* d_in, const int* in_sizes, int n_in,
                              void* d_out, int out_size, void* d_ws, size_t ws_size,
                              hipStream_t stream){
  const float* x   = (const float*)d_in[0];
  const float* g1  = (const float*)d_in[1];
  const float* be1 = (const float*)d_in[2];
  const float* W1  = (const float*)d_in[3];
  const float* b1  = (const float*)d_in[4];
  const float* g2  = (const float*)d_in[5];
  const float* be2 = (const float*)d_in[6];
  const float* W2  = (const float*)d_in[7];
  const float* b2  = (const float*)d_in[8];
  const float* W3  = (const float*)d_in[9];
  const float* b3  = (const float*)d_in[10];
  float* out = (float*)d_out;

  char* ws = (char*)d_ws;
  size_t off = 0;
  auto alloc = [&](size_t bytes) -> void* {
    void* p = ws + off;
    off += (bytes + 255) & ~(size_t)255;
    return p;
  };
  u16*    xn    = (u16*)   alloc((size_t)1605632*2);   // LN1 out, bf16
  u16*    y     = (u16*)   alloc((size_t)9633792*2);   // [6272][1536] bf16; reused for zT+z
  float2* stats = (float2*)alloc((size_t)6272*8);      // LN2 (m, rstd)
  u16*    yT    = (u16*)   alloc((size_t)9633792*2);   // [1536][6272] bf16
  if (off > ws_size) return;

  u16* zT = y;                 // [768][6272] bf16 (y dead by kSGU)
  u16* z  = y + 4816896;       // [6272][768] bf16

  kLN1   <<<6272, 256, 0, stream>>>(x, g1, be1, xn);
  kExpand<<<1176, 256, 0, stream>>>(xn, W1, b1, y);
  kStats2<<<6272, 256, 0, stream>>>(y, stats);
  kTrans <<<2352, 256, 0, stream>>>(y, yT, 6272, 1536, stats, g2, be2);
  kSGU   <<<768,  256, 0, stream>>>(yT, W2, b2, zT);
  kTrans <<<1176, 256, 0, stream>>>(zT, z, 768, 6272, nullptr, nullptr, nullptr);
  kOutF  <<<196,  512, 0, stream>>>(z, W3, b3, x, out);
}